// Round 7
// baseline (547.341 us; speedup 1.0000x reference)
//
#include <hip/hip_runtime.h>
#include <hip/hip_bf16.h>
#include <math.h>

#define N_NODES 50000
#define N_EDGES 600000
// IN_DIM=128, EDGE_DIM=64; e = relu(U[src] + V[dst] + ef@We + b_pre)

typedef __attribute__((ext_vector_type(8))) short short8v;   // 8 bf16 MFMA A/B frag
typedef __attribute__((ext_vector_type(4))) short short4v;
typedef __attribute__((ext_vector_type(4))) float f32x4;     // MFMA C/D frag
typedef __attribute__((ext_vector_type(4))) float float4v;
typedef __attribute__((ext_vector_type(4))) unsigned int uint4v;

#define FLT_BIG 3.402823466e38f

__device__ __forceinline__ short f2bf(float f) {
  unsigned int u = __float_as_uint(f);
  u = (u + 0x7FFFu + ((u >> 16) & 1u)) >> 16;   // RNE
  return (short)u;
}
__device__ __forceinline__ float bf2f(unsigned short s) {
  return __uint_as_float(((unsigned int)s) << 16);
}

// ---- init: zero sum/sq/mx, FLT_MAX mn, zero deg (one kernel, 4 planes + deg)
__global__ void init_kernel(uint4v* __restrict__ base) {
  const long nz = 4800000;   // 3*P/4 uint4 (sum,sq,mx)
  const long nm = 1600000;   // P/4    (mn = FLT_MAX; NOT inf: 0*inf=NaN hazard)
  const long nd = 12512;     // deg 50048 ints
  uint4v z = {0u, 0u, 0u, 0u};
  uint4v f = {0x7F7FFFFFu, 0x7F7FFFFFu, 0x7F7FFFFFu, 0x7F7FFFFFu};
  long i = (long)blockIdx.x * blockDim.x + threadIdx.x;
  long stride = (long)gridDim.x * blockDim.x;
  for (; i < nz + nm + nd; i += stride) base[i] = (i >= nz && i < nz + nm) ? f : z;
}

// ---- weights: WuvT[256][128], WeT[128][64], Wp1T[128][1664], Wp2T[128][128]
__global__ void conv_w_kernel(const float* __restrict__ Wpre, const float* __restrict__ Wp1,
                              const float* __restrict__ Wp2, short* __restrict__ WuvT,
                              short* __restrict__ WeT, short* __restrict__ Wp1T,
                              short* __restrict__ Wp2T) {
  int idx = blockIdx.x * 256 + threadIdx.x;
  if (idx < 32768) {                       // WuvT: row c (<128:U, >=128:V), col k
    int c = idx >> 7, k = idx & 127;
    WuvT[idx] = f2bf(Wpre[(k + ((c >> 7) << 7)) * 128 + (c & 127)]);
  } else if (idx < 40960) {                // WeT
    int o = idx - 32768, n = o >> 6, k = o & 63;
    WeT[o] = f2bf(Wpre[(256 + k) * 128 + n]);
  } else if (idx < 253952) {               // Wp1T
    int o = idx - 40960, n = o / 1664, k = o % 1664;
    Wp1T[o] = f2bf(Wp1[k * 128 + n]);
  } else if (idx < 270336) {               // Wp2T
    int o = idx - 253952, n = o >> 7, k = o & 127;
    Wp2T[o] = f2bf(Wp2[k * 128 + n]);
  }
}

// ---- degree histogram ------------------------------------------------------
__global__ void deg_kernel(const int* __restrict__ dst, int* __restrict__ deg) {
  int i = blockIdx.x * blockDim.x + threadIdx.x;
  int stride = gridDim.x * blockDim.x;
  for (; i < N_EDGES; i += stride) atomicAdd(deg + dst[i], 1);
}

// ---- exclusive scan of deg -> cursor (single block) ------------------------
__global__ __launch_bounds__(1024) void scan_kernel(const int* __restrict__ deg,
                                                    int* __restrict__ cursor) {
  __shared__ int part[1024];
  const int CH = 49;
  int t = threadIdx.x;
  int base = t * CH;
  int s = 0;
  for (int i = 0; i < CH; i++) {
    int idx = base + i;
    if (idx < N_NODES) s += deg[idx];
  }
  part[t] = s;
  __syncthreads();
  for (int off = 1; off < 1024; off <<= 1) {
    int v = (t >= off) ? part[t - off] : 0;
    __syncthreads();
    part[t] += v;
    __syncthreads();
  }
  int ex = (t == 0) ? 0 : part[t - 1];
  for (int i = 0; i < CH; i++) {
    int idx = base + i;
    if (idx < N_NODES) {
      cursor[idx] = ex;
      ex += deg[idx];
    }
  }
}

// ---- scatter: perm + sorted src/dst ----------------------------------------
__global__ void scatter_kernel(const int* __restrict__ src, const int* __restrict__ dst,
                               int* __restrict__ cursor, int* __restrict__ perm,
                               int* __restrict__ srcS, int* __restrict__ dstS) {
  int i = blockIdx.x * blockDim.x + threadIdx.x;
  int stride = gridDim.x * blockDim.x;
  for (; i < N_EDGES; i += stride) {
    int d = dst[i];
    int pos = atomicAdd(cursor + d, 1);
    perm[pos] = i;
    srcS[pos] = src[i];
    dstS[pos] = d;
  }
}

// ---- UV kernel: [U|V] = x @ [Ws|Wd], dense 50K x 128 -> 256, bf16 out ------
__global__ __launch_bounds__(256) void uv_kernel(const float* __restrict__ nf,
                                                 const short* __restrict__ WuvT,
                                                 short* __restrict__ UV) {
  __shared__ short A[64][136];
  int t = threadIdx.x;
  int lane = t & 63, w = t >> 6;
  int r15 = lane & 15, g = lane >> 4;
  int nb = blockIdx.x * 64;

#pragma unroll
  for (int i = 0; i < 8; i++) {
    int u = t + 256 * i, row = u >> 5, q = u & 31;
    int gn = min(nb + row, N_NODES - 1);
    float4v a = *(const float4v*)(nf + (size_t)gn * 128 + q * 4);
    short4v s;
    s[0] = f2bf(a[0]); s[1] = f2bf(a[1]); s[2] = f2bf(a[2]); s[3] = f2bf(a[3]);
    *(short4v*)(&A[row][q * 4]) = s;
  }
  __syncthreads();

  f32x4 acc[4][4];
#pragma unroll
  for (int m = 0; m < 4; m++)
#pragma unroll
    for (int j = 0; j < 4; j++) acc[m][j] = (f32x4){0.f, 0.f, 0.f, 0.f};

#pragma unroll
  for (int ks = 0; ks < 4; ks++) {
    short8v af[4];
#pragma unroll
    for (int m = 0; m < 4; m++) af[m] = *(const short8v*)(&A[m * 16 + r15][ks * 32 + 8 * g]);
#pragma unroll
    for (int j = 0; j < 4; j++) {
      short8v bf = *(const short8v*)(WuvT + (size_t)((4 * w + j) * 16 + r15) * 128 + ks * 32 + 8 * g);
#pragma unroll
      for (int m = 0; m < 4; m++)
        acc[m][j] = __builtin_amdgcn_mfma_f32_16x16x32_bf16(af[m], bf, acc[m][j], 0, 0, 0);
    }
  }

#pragma unroll
  for (int m = 0; m < 4; m++)
#pragma unroll
    for (int j = 0; j < 4; j++)
#pragma unroll
      for (int r = 0; r < 4; r++) {
        int node = nb + m * 16 + 4 * g + r;
        if (node < N_NODES)
          UV[(size_t)node * 256 + (4 * w + j) * 16 + r15] = f2bf(acc[m][j][r]);
      }
}

// ---- edge kernel: K=64 MFMA (F = ef@We) + u/v direct loads + seg reduce ----
__global__ __launch_bounds__(256, 6) void edge_kernel(
    const int* __restrict__ perm, const int* __restrict__ srcS, const int* __restrict__ dstS,
    const float* __restrict__ edge_feat, const float* __restrict__ b_pre,
    const short* __restrict__ UV, const short* __restrict__ WeT,
    float* __restrict__ sum, float* __restrict__ sq,
    unsigned int* __restrict__ mx, unsigned int* __restrict__ mn) {
  __shared__ short A[32][72];    // 32 edges x 64 k (pad 8) = 4.6 KB
  __shared__ float E[32][132];   // F contribution, f32 (pad 4) = 16.9 KB

  int t = threadIdx.x;
  int lane = t & 63, w = t >> 6;
  int r15 = lane & 15, g = lane >> 4;

  short8v bfr[2][2];             // only 16 VGPRs of weights (was 80)
#pragma unroll
  for (int ks = 0; ks < 2; ks++)
#pragma unroll
    for (int j = 0; j < 2; j++)
      bfr[ks][j] = *(const short8v*)(WeT + (size_t)((2 * w + j) * 16 + r15) * 64 + ks * 32 + 8 * g);
  float bpc = b_pre[t & 127];

  const int G = gridDim.x;
  const int nchunks = N_EDGES / 32;  // 18750
  int ch = blockIdx.x;
  if (ch >= nchunks) return;

  float4v ge[2];
  auto LOADE = [&](int chunk) {
    int e0c = min(chunk, nchunks - 1) * 32;
#pragma unroll
    for (int i = 0; i < 2; i++) {
      int u = t + 256 * i, e = u >> 4, q = u & 15;
      ge[i] = *(const float4v*)(edge_feat + (size_t)perm[e0c + e] * 64 + q * 4);
    }
  };
  auto WRITE_A = [&]() {
#pragma unroll
    for (int i = 0; i < 2; i++) {
      int u = t + 256 * i, e = u >> 4, q = u & 15;
      short4v s4;
      s4[0] = f2bf(ge[i][0]); s4[1] = f2bf(ge[i][1]);
      s4[2] = f2bf(ge[i][2]); s4[3] = f2bf(ge[i][3]);
      *(short4v*)(&A[e][q * 4]) = s4;
    }
  };

  LOADE(ch);
  WRITE_A();
  __syncthreads();

  for (; ch < nchunks; ch += G) {
    int e0 = ch * 32;
    // ==== P1: MFMA A -> E; issue next gathers ====
    f32x4 acc[2][2];
#pragma unroll
    for (int m = 0; m < 2; m++)
#pragma unroll
      for (int j = 0; j < 2; j++) acc[m][j] = (f32x4){0.f, 0.f, 0.f, 0.f};
#pragma unroll
    for (int m = 0; m < 2; m++)
#pragma unroll
      for (int ks = 0; ks < 2; ks++) {
        short8v af = *(const short8v*)(&A[m * 16 + r15][ks * 32 + 8 * g]);
        acc[m][0] = __builtin_amdgcn_mfma_f32_16x16x32_bf16(af, bfr[ks][0], acc[m][0], 0, 0, 0);
        acc[m][1] = __builtin_amdgcn_mfma_f32_16x16x32_bf16(af, bfr[ks][1], acc[m][1], 0, 0, 0);
      }
    LOADE(ch + G);  // in flight across barrier + scan (8 VGPR payload, no spill)
#pragma unroll
    for (int m = 0; m < 2; m++)
#pragma unroll
      for (int j = 0; j < 2; j++)
#pragma unroll
        for (int r = 0; r < 4; r++)
          E[m * 16 + 4 * g + r][(2 * w + j) * 16 + r15] = acc[m][j][r];
    __syncthreads();  // B1: E ready, A free

    // ==== P2: e = relu(U[src]+V[dst]+E+b); seg-reduce; stage next A ====
    {
      unsigned int bm;
      {
        int l = lane & 31;
        int d = dstS[e0 + l];
        int dn = dstS[e0 + l + 1];
        bm = (unsigned int)__ballot(d != dn) | 0x80000000u;
      }
      int c = t & 127, half = t >> 7;  // half 0: sum+sq, 1: max+min
      float a0 = (half == 0) ? 0.f : -FLT_BIG;
      float a1 = (half == 0) ? 0.f : FLT_BIG;
      bool firstseg = true;
#pragma unroll
      for (int r = 0; r < 32; r++) {
        int sr = srcS[e0 + r], dr = dstS[e0 + r];
        float u = bf2f(((const unsigned short*)UV)[(size_t)sr * 256 + c]);
        float v = bf2f(((const unsigned short*)UV)[(size_t)dr * 256 + 128 + c]);
        float e = fmaxf(u + v + E[r][c] + bpc, 0.f);
        if (half == 0) { a0 += e; a1 += e * e; }
        else { a0 = fmaxf(a0, e); a1 = fminf(a1, e); }
        if ((bm >> r) & 1u) {  // wave-uniform branch
          size_t o = (size_t)dr * 128 + c;
          bool bnd = firstseg || (r == 31);
          if (half == 0) {
            if (bnd) { atomicAdd(sum + o, a0); atomicAdd(sq + o, a1); }
            else { sum[o] = a0; sq[o] = a1; }
            a0 = 0.f; a1 = 0.f;
          } else {
            if (bnd) { atomicMax(mx + o, __float_as_uint(a0)); atomicMin(mn + o, __float_as_uint(a1)); }
            else { ((float*)mx)[o] = a0; ((float*)mn)[o] = a1; }
            a0 = -FLT_BIG; a1 = FLT_BIG;
          }
          firstseg = false;
        }
      }
    }
    WRITE_A();
    __syncthreads();  // B2
  }
}

// ---- post kernel: scaler-factored GEMM over K=640 (x | agg), fused MLP2 ----
__global__ __launch_bounds__(256) void post_kernel(
    const float* __restrict__ node_feat, const int* __restrict__ deg,
    const float* __restrict__ sum, const float* __restrict__ sq,
    const float* __restrict__ mxp, const float* __restrict__ mnp,
    const short* __restrict__ Wp1T, const short* __restrict__ Wp2T,
    const float* __restrict__ b1, const float* __restrict__ b2,
    float* __restrict__ out) {
  __shared__ short Ab[2][64][64];
  __shared__ short T[64][136];
  __shared__ float scalL[64][4];
  int t = threadIdx.x;
  int lane = t & 63, w = t >> 6;
  int r15 = lane & 15, g = lane >> 4;
  int nb = blockIdx.x * 64;

  if (t < 64) {
    int n = min(nb + t, N_NODES - 1);
    float dg = (float)deg[n];
    scalL[t][0] = 1.f / fmaxf(dg, 1.f);
    float logd = logf(dg + 1.f);
    scalL[t][1] = logd * 0.4f;
    scalL[t][2] = (dg > 0.f) ? 2.5f / fmaxf(logd, 1e-5f) : 0.f;
    scalL[t][3] = (dg > 0.f) ? 1.f : 0.f;
  }
  float bb1[2];
  bb1[0] = b1[2 * w * 16 + r15];
  bb1[1] = b1[(2 * w + 1) * 16 + r15];

  f32x4 accB[4][2], accC[4][2], accD[4][2];
#pragma unroll
  for (int m = 0; m < 4; m++)
#pragma unroll
    for (int j = 0; j < 2; j++) {
      accB[m][j] = (f32x4){0.f, 0.f, 0.f, 0.f};
      accC[m][j] = (f32x4){0.f, 0.f, 0.f, 0.f};
      accD[m][j] = (f32x4){0.f, 0.f, 0.f, 0.f};
    }

  auto STAGE = [&](int buf, int c) {
#pragma unroll
    for (int i = 0; i < 2; i++) {
      int row = i * 32 + (t >> 3);
      int gn = min(nb + row, N_NODES - 1);
      int s8 = t & 7;
      short* lp = &Ab[buf][0][0] + row * 64 + (s8 ^ (row & 7)) * 8;
      if (c < 2) {
        const float* np = node_feat + (size_t)gn * 128 + c * 64 + s8 * 8;
        float4v a = *(const float4v*)np, b = *(const float4v*)(np + 4);
        short8v pk;
#pragma unroll
        for (int r = 0; r < 4; r++) { pk[r] = f2bf(a[r]); pk[4 + r] = f2bf(b[r]); }
        *(short8v*)lp = pk;
      } else {
        size_t o = (size_t)gn * 128 + (c & 1) * 64 + s8 * 8;
        int si = (c - 2) >> 1;
        float inv = scalL[row][0], has = scalL[row][3];
        short8v pk;
        if (si == 0) {
          float4v a = *(const float4v*)(sum + o), b = *(const float4v*)(sum + o + 4);
#pragma unroll
          for (int r = 0; r < 4; r++) { pk[r] = f2bf(a[r] * inv); pk[4 + r] = f2bf(b[r] * inv); }
        } else if (si == 1) {
          float4v a = *(const float4v*)(mxp + o), b = *(const float4v*)(mxp + o + 4);
#pragma unroll
          for (int r = 0; r < 4; r++) { pk[r] = f2bf(a[r]); pk[4 + r] = f2bf(b[r]); }
        } else if (si == 2) {
          float4v a = *(const float4v*)(mnp + o), b = *(const float4v*)(mnp + o + 4);
          bool h = (has != 0.f);  // SELECT, not multiply (0*FLT_MAX safe, 0*inf was NaN)
#pragma unroll
          for (int r = 0; r < 4; r++) {
            pk[r] = f2bf(h ? a[r] : 0.f);
            pk[4 + r] = f2bf(h ? b[r] : 0.f);
          }
        } else {
          float4v a = *(const float4v*)(sum + o), b = *(const float4v*)(sum + o + 4);
          float4v qa = *(const float4v*)(sq + o), qb = *(const float4v*)(sq + o + 4);
#pragma unroll
          for (int r = 0; r < 4; r++) {
            float m0 = a[r] * inv, m1 = b[r] * inv;
            pk[r] = f2bf(has * sqrtf(fmaxf(qa[r] * inv - m0 * m0, 0.f) + 1e-5f));
            pk[4 + r] = f2bf(has * sqrtf(fmaxf(qb[r] * inv - m1 * m1, 0.f) + 1e-5f));
          }
        }
        *(short8v*)lp = pk;
      }
    }
  };

  auto COMPUTE = [&](int buf, int c) {
    const short* base = &Ab[buf][0][0];
#pragma unroll
    for (int ks2 = 0; ks2 < 2; ks2++) {
      short8v af[4];
#pragma unroll
      for (int m = 0; m < 4; m++) {
        int row = m * 16 + r15;
        af[m] = *(const short8v*)(base + row * 64 + (((ks2 << 2) | g) ^ (row & 7)) * 8);
      }
      if (c < 2) {
        int kcol = c * 64 + ks2 * 32;
#pragma unroll
        for (int j = 0; j < 2; j++) {
          short8v bf = *(const short8v*)(Wp1T + (size_t)((2 * w + j) * 16 + r15) * 1664 + kcol + 8 * g);
#pragma unroll
          for (int m = 0; m < 4; m++)
            accB[m][j] = __builtin_amdgcn_mfma_f32_16x16x32_bf16(af[m], bf, accB[m][j], 0, 0, 0);
        }
      } else {
        int kagg = (c - 2) * 64 + ks2 * 32;
#pragma unroll
        for (int j = 0; j < 2; j++) {
          const short* wr = Wp1T + (size_t)((2 * w + j) * 16 + r15) * 1664 + 8 * g;
          short8v bb = *(const short8v*)(wr + 128 + kagg);
          short8v bc = *(const short8v*)(wr + 640 + kagg);
          short8v bd = *(const short8v*)(wr + 1152 + kagg);
#pragma unroll
          for (int m = 0; m < 4; m++) {
            accB[m][j] = __builtin_amdgcn_mfma_f32_16x16x32_bf16(af[m], bb, accB[m][j], 0, 0, 0);
            accC[m][j] = __builtin_amdgcn_mfma_f32_16x16x32_bf16(af[m], bc, accC[m][j], 0, 0, 0);
            accD[m][j] = __builtin_amdgcn_mfma_f32_16x16x32_bf16(af[m], bd, accD[m][j], 0, 0, 0);
          }
        }
      }
    }
  };

  STAGE(0, 0);
  __syncthreads();
#pragma unroll
  for (int c = 0; c < 10; c++) {
    if (c < 9) STAGE((c + 1) & 1, c + 1);
    COMPUTE(c & 1, c);
    __syncthreads();
  }

#pragma unroll
  for (int m = 0; m < 4; m++)
#pragma unroll
    for (int j = 0; j < 2; j++)
#pragma unroll
      for (int r = 0; r < 4; r++) {
        int row = m * 16 + 4 * g + r;
        float v = accB[m][j][r] + scalL[row][1] * accC[m][j][r] + scalL[row][2] * accD[m][j][r] +
                  bb1[j];
        T[row][(2 * w + j) * 16 + r15] = f2bf(fmaxf(v, 0.f));
      }
  __syncthreads();

  f32x4 acc2[4][2];
#pragma unroll
  for (int m = 0; m < 4; m++)
#pragma unroll
    for (int j = 0; j < 2; j++) acc2[m][j] = (f32x4){0.f, 0.f, 0.f, 0.f};
#pragma unroll
  for (int ks = 0; ks < 4; ks++) {
    short8v af2[4], b2f[2];
#pragma unroll
    for (int m = 0; m < 4; m++) af2[m] = *(const short8v*)(&T[m * 16 + r15][ks * 32 + 8 * g]);
#pragma unroll
    for (int j = 0; j < 2; j++)
      b2f[j] = *(const short8v*)(Wp2T + (size_t)((2 * w + j) * 16 + r15) * 128 + ks * 32 + 8 * g);
#pragma unroll
    for (int m = 0; m < 4; m++)
#pragma unroll
      for (int j = 0; j < 2; j++)
        acc2[m][j] = __builtin_amdgcn_mfma_f32_16x16x32_bf16(af2[m], b2f[j], acc2[m][j], 0, 0, 0);
  }

#pragma unroll
  for (int m = 0; m < 4; m++)
#pragma unroll
    for (int j = 0; j < 2; j++)
#pragma unroll
      for (int r = 0; r < 4; r++) {
        int row = m * 16 + 4 * g + r;
        int gn = nb + row;
        if (gn < N_NODES) {
          int col = (2 * w + j) * 16 + r15;
          size_t o = (size_t)gn * 128 + col;
          out[o] = acc2[m][j][r] + b2[col] + node_feat[o];
        }
      }
}

extern "C" void kernel_launch(void* const* d_in, const int* in_sizes, int n_in,
                              void* d_out, int out_size, void* d_ws, size_t ws_size,
                              hipStream_t stream) {
  const float* node_feat = (const float*)d_in[0];
  const float* edge_feat = (const float*)d_in[1];
  const int* src = (const int*)d_in[2];
  const int* dst = (const int*)d_in[3];
  const float* W_pre = (const float*)d_in[4];
  const float* b_pre = (const float*)d_in[5];
  const float* W_post1 = (const float*)d_in[6];
  const float* b_post1 = (const float*)d_in[7];
  const float* W_post2 = (const float*)d_in[8];
  const float* b_post2 = (const float*)d_in[9];
  float* out = (float*)d_out;

  char* ws = (char*)d_ws;
  size_t P = (size_t)N_NODES * 128;
  float* sum = (float*)ws;
  float* sq = sum + P;
  float* mx = sq + P;
  float* mn = mx + P;
  int* deg = (int*)(mn + P);
  int* cursor = deg + 50048;
  int* perm = cursor + 50048;
  int* srcS = perm + 600064;
  int* dstS = srcS + 600064;
  short* UV = (short*)(dstS + 600064);   // 50048*256 bf16
  short* WuvT = UV + (size_t)50048 * 256;
  short* WeT = WuvT + 32768;
  short* Wp1T = WeT + 8192;
  short* Wp2T = Wp1T + 212992;
  size_t needed = (size_t)((char*)(Wp2T + 16384) - ws);
  if (ws_size < needed) return;

  init_kernel<<<2048, 256, 0, stream>>>((uint4v*)ws);
  conv_w_kernel<<<(270336 + 255) / 256, 256, 0, stream>>>(W_pre, W_post1, W_post2, WuvT, WeT,
                                                          Wp1T, Wp2T);
  deg_kernel<<<1024, 256, 0, stream>>>(dst, deg);
  scan_kernel<<<1, 1024, 0, stream>>>(deg, cursor);
  scatter_kernel<<<1024, 256, 0, stream>>>(src, dst, cursor, perm, srcS, dstS);
  uv_kernel<<<(N_NODES + 63) / 64, 256, 0, stream>>>(node_feat, WuvT, UV);
  edge_kernel<<<3750, 256, 0, stream>>>(perm, srcS, dstS, edge_feat, b_pre, UV, WeT, sum, sq,
                                        (unsigned int*)mx, (unsigned int*)mn);
  post_kernel<<<(N_NODES + 63) / 64, 256, 0, stream>>>(node_feat, deg, sum, sq, mx, mn, Wp1T,
                                                       Wp2T, b_post1, b_post2, out);
}

// Round 8
// 407.972 us; speedup vs baseline: 1.3416x; 1.3416x over previous
//
#include <hip/hip_runtime.h>
#include <hip/hip_bf16.h>
#include <math.h>

#define N_NODES 50000
#define N_EDGES 600000
// IN_DIM=128, EDGE_DIM=64; e = relu(U[src] + V[dst] + ef@We + b_pre)

typedef __attribute__((ext_vector_type(8))) short short8v;   // 8 bf16 MFMA A/B frag
typedef __attribute__((ext_vector_type(4))) short short4v;
typedef __attribute__((ext_vector_type(4))) float f32x4;     // MFMA C/D frag
typedef __attribute__((ext_vector_type(4))) float float4v;
typedef __attribute__((ext_vector_type(4))) unsigned int uint4v;

#define FLT_BIG 3.402823466e38f

__device__ __forceinline__ short f2bf(float f) {
  unsigned int u = __float_as_uint(f);
  u = (u + 0x7FFFu + ((u >> 16) & 1u)) >> 16;   // RNE
  return (short)u;
}
__device__ __forceinline__ float bf2f(unsigned short s) {
  return __uint_as_float(((unsigned int)s) << 16);
}

// ---- init: zero sum/sq/mx, FLT_MAX mn, zero deg (one kernel, 4 planes + deg)
__global__ void init_kernel(uint4v* __restrict__ base) {
  const long nz = 4800000;   // 3*P/4 uint4 (sum,sq,mx)
  const long nm = 1600000;   // P/4    (mn = FLT_MAX; NOT inf: 0*inf=NaN hazard)
  const long nd = 12512;     // deg 50048 ints
  uint4v z = {0u, 0u, 0u, 0u};
  uint4v f = {0x7F7FFFFFu, 0x7F7FFFFFu, 0x7F7FFFFFu, 0x7F7FFFFFu};
  long i = (long)blockIdx.x * blockDim.x + threadIdx.x;
  long stride = (long)gridDim.x * blockDim.x;
  for (; i < nz + nm + nd; i += stride) base[i] = (i >= nz && i < nz + nm) ? f : z;
}

// ---- weights: WuvT[256][128], WeT[128][64], Wp1T[128][1664], Wp2T[128][128]
__global__ void conv_w_kernel(const float* __restrict__ Wpre, const float* __restrict__ Wp1,
                              const float* __restrict__ Wp2, short* __restrict__ WuvT,
                              short* __restrict__ WeT, short* __restrict__ Wp1T,
                              short* __restrict__ Wp2T) {
  int idx = blockIdx.x * 256 + threadIdx.x;
  if (idx < 32768) {                       // WuvT: row c (<128:U, >=128:V), col k
    int c = idx >> 7, k = idx & 127;
    WuvT[idx] = f2bf(Wpre[(k + ((c >> 7) << 7)) * 128 + (c & 127)]);
  } else if (idx < 40960) {                // WeT
    int o = idx - 32768, n = o >> 6, k = o & 63;
    WeT[o] = f2bf(Wpre[(256 + k) * 128 + n]);
  } else if (idx < 253952) {               // Wp1T
    int o = idx - 40960, n = o / 1664, k = o % 1664;
    Wp1T[o] = f2bf(Wp1[k * 128 + n]);
  } else if (idx < 270336) {               // Wp2T
    int o = idx - 253952, n = o >> 7, k = o & 127;
    Wp2T[o] = f2bf(Wp2[k * 128 + n]);
  }
}

// ---- degree histogram ------------------------------------------------------
__global__ void deg_kernel(const int* __restrict__ dst, int* __restrict__ deg) {
  int i = blockIdx.x * blockDim.x + threadIdx.x;
  int stride = gridDim.x * blockDim.x;
  for (; i < N_EDGES; i += stride) atomicAdd(deg + dst[i], 1);
}

// ---- exclusive scan of deg -> cursor (single block) ------------------------
__global__ __launch_bounds__(1024) void scan_kernel(const int* __restrict__ deg,
                                                    int* __restrict__ cursor) {
  __shared__ int part[1024];
  const int CH = 49;
  int t = threadIdx.x;
  int base = t * CH;
  int s = 0;
  for (int i = 0; i < CH; i++) {
    int idx = base + i;
    if (idx < N_NODES) s += deg[idx];
  }
  part[t] = s;
  __syncthreads();
  for (int off = 1; off < 1024; off <<= 1) {
    int v = (t >= off) ? part[t - off] : 0;
    __syncthreads();
    part[t] += v;
    __syncthreads();
  }
  int ex = (t == 0) ? 0 : part[t - 1];
  for (int i = 0; i < CH; i++) {
    int idx = base + i;
    if (idx < N_NODES) {
      cursor[idx] = ex;
      ex += deg[idx];
    }
  }
}

// ---- scatter: perm + sorted src/dst ----------------------------------------
__global__ void scatter_kernel(const int* __restrict__ src, const int* __restrict__ dst,
                               int* __restrict__ cursor, int* __restrict__ perm,
                               int* __restrict__ srcS, int* __restrict__ dstS) {
  int i = blockIdx.x * blockDim.x + threadIdx.x;
  int stride = gridDim.x * blockDim.x;
  for (; i < N_EDGES; i += stride) {
    int d = dst[i];
    int pos = atomicAdd(cursor + d, 1);
    perm[pos] = i;
    srcS[pos] = src[i];
    dstS[pos] = d;
  }
}

// ---- UV kernel: [U|V] = x @ [Ws|Wd], dense 50K x 128 -> 256, bf16 out ------
__global__ __launch_bounds__(256) void uv_kernel(const float* __restrict__ nf,
                                                 const short* __restrict__ WuvT,
                                                 short* __restrict__ UV) {
  __shared__ short A[64][136];
  int t = threadIdx.x;
  int lane = t & 63, w = t >> 6;
  int r15 = lane & 15, g = lane >> 4;
  int nb = blockIdx.x * 64;

#pragma unroll
  for (int i = 0; i < 8; i++) {
    int u = t + 256 * i, row = u >> 5, q = u & 31;
    int gn = min(nb + row, N_NODES - 1);
    float4v a = *(const float4v*)(nf + (size_t)gn * 128 + q * 4);
    short4v s;
    s[0] = f2bf(a[0]); s[1] = f2bf(a[1]); s[2] = f2bf(a[2]); s[3] = f2bf(a[3]);
    *(short4v*)(&A[row][q * 4]) = s;
  }
  __syncthreads();

  f32x4 acc[4][4];
#pragma unroll
  for (int m = 0; m < 4; m++)
#pragma unroll
    for (int j = 0; j < 4; j++) acc[m][j] = (f32x4){0.f, 0.f, 0.f, 0.f};

#pragma unroll
  for (int ks = 0; ks < 4; ks++) {
    short8v af[4];
#pragma unroll
    for (int m = 0; m < 4; m++) af[m] = *(const short8v*)(&A[m * 16 + r15][ks * 32 + 8 * g]);
#pragma unroll
    for (int j = 0; j < 4; j++) {
      short8v bf = *(const short8v*)(WuvT + (size_t)((4 * w + j) * 16 + r15) * 128 + ks * 32 + 8 * g);
#pragma unroll
      for (int m = 0; m < 4; m++)
        acc[m][j] = __builtin_amdgcn_mfma_f32_16x16x32_bf16(af[m], bf, acc[m][j], 0, 0, 0);
    }
  }

#pragma unroll
  for (int m = 0; m < 4; m++)
#pragma unroll
    for (int j = 0; j < 4; j++)
#pragma unroll
      for (int r = 0; r < 4; r++) {
        int node = nb + m * 16 + 4 * g + r;
        if (node < N_NODES)
          UV[(size_t)node * 256 + (4 * w + j) * 16 + r15] = f2bf(acc[m][j][r]);
      }
}

// ---- edge kernel: full-chunk UV prefetch in P1; LDS-only serial scan -------
__global__ __launch_bounds__(256, 6) void edge_kernel(
    const int* __restrict__ perm, const int* __restrict__ srcS, const int* __restrict__ dstS,
    const float* __restrict__ edge_feat, const float* __restrict__ b_pre,
    const short* __restrict__ UV, const short* __restrict__ WeT,
    float* __restrict__ sum, float* __restrict__ sq,
    unsigned int* __restrict__ mx, unsigned int* __restrict__ mn) {
  __shared__ short A[32][72];        // 32 edges x 64 k (pad 8) = 4.6 KB
  __shared__ float E[32][132];       // F, then in-place e (pad 4) = 16.9 KB
  __shared__ int srcL[2][32], dstL[2][32];  // idx double-buffer, 512 B

  int t = threadIdx.x;
  int lane = t & 63, w = t >> 6;
  int r15 = lane & 15, g = lane >> 4;

  short8v bfr[2][2];                 // 16 VGPRs of We weights
#pragma unroll
  for (int ks = 0; ks < 2; ks++)
#pragma unroll
    for (int j = 0; j < 2; j++)
      bfr[ks][j] = *(const short8v*)(WeT + (size_t)((2 * w + j) * 16 + r15) * 64 + ks * 32 + 8 * g);

  int c = t & 127, half = t >> 7;    // scan role: col, stat-pair
  int cd = t & 63, wrow = t >> 6;    // e-compute role: col-pair, row-group
  float bp0 = b_pre[2 * cd], bp1 = b_pre[2 * cd + 1];

  const unsigned short* UVu = (const unsigned short*)UV;
  const int G = gridDim.x;
  const int nchunks = N_EDGES / 32;  // 18750
  int ch = blockIdx.x;
  if (ch >= nchunks) return;

  float4v ge[2];
  auto LOADE = [&](int chunk) {
    int e0c = min(chunk, nchunks - 1) * 32;
#pragma unroll
    for (int i = 0; i < 2; i++) {
      int u = t + 256 * i, e = u >> 4, q = u & 15;
      ge[i] = *(const float4v*)(edge_feat + (size_t)perm[e0c + e] * 64 + q * 4);
    }
  };
  auto WRITE_A = [&]() {
#pragma unroll
    for (int i = 0; i < 2; i++) {
      int u = t + 256 * i, e = u >> 4, q = u & 15;
      short4v s4;
      s4[0] = f2bf(ge[i][0]); s4[1] = f2bf(ge[i][1]);
      s4[2] = f2bf(ge[i][2]); s4[3] = f2bf(ge[i][3]);
      *(short4v*)(&A[e][q * 4]) = s4;
    }
  };

  int nsrc = 0, ndst = 0;
  auto IDXLOAD = [&](int chunk) {
    if (t < 32) {
      int e0c = min(chunk, nchunks - 1) * 32 + t;
      nsrc = srcS[e0c];
      ndst = dstS[e0c];
    }
  };

  // prologue: stage chunk ch (A + idx); preload idx(ch+G) into regs
  LOADE(ch);
  IDXLOAD(ch);
  if (t < 32) { srcL[0][t] = nsrc; dstL[0][t] = ndst; }
  WRITE_A();
  IDXLOAD(ch + G);
  __syncthreads();

  int p = 0;
  for (; ch < nchunks; ch += G) {
    // ==== P1: issue whole-chunk UV prefetch (16 dwords/thread); MFMA; ====
    // ==== issue next-chunk edge gathers.  Loads land by B1's vmcnt drain. ===
    unsigned int upf[8], vpf[8];
#pragma unroll
    for (int i = 0; i < 8; i++) {
      int r = wrow + 4 * i;
      int sr = srcL[p][r], dr = dstL[p][r];
      upf[i] = *(const unsigned int*)(UVu + (size_t)sr * 256 + 2 * cd);
      vpf[i] = *(const unsigned int*)(UVu + (size_t)dr * 256 + 128 + 2 * cd);
    }
    LOADE(ch + G);

    f32x4 acc[2][2];
#pragma unroll
    for (int m = 0; m < 2; m++)
#pragma unroll
      for (int j = 0; j < 2; j++) acc[m][j] = (f32x4){0.f, 0.f, 0.f, 0.f};
#pragma unroll
    for (int m = 0; m < 2; m++)
#pragma unroll
      for (int ks = 0; ks < 2; ks++) {
        short8v af = *(const short8v*)(&A[m * 16 + r15][ks * 32 + 8 * g]);
        acc[m][0] = __builtin_amdgcn_mfma_f32_16x16x32_bf16(af, bfr[ks][0], acc[m][0], 0, 0, 0);
        acc[m][1] = __builtin_amdgcn_mfma_f32_16x16x32_bf16(af, bfr[ks][1], acc[m][1], 0, 0, 0);
      }
#pragma unroll
    for (int m = 0; m < 2; m++)
#pragma unroll
      for (int j = 0; j < 2; j++)
#pragma unroll
        for (int r = 0; r < 4; r++)
          E[m * 16 + 4 * g + r][(2 * w + j) * 16 + r15] = acc[m][j][r];
    __syncthreads();  // B1: E(F) ready; A free; all prefetches landed

    // ==== P2a: e = relu(u + v + F + b) in place (pure VALU + LDS) ====
#pragma unroll
    for (int i = 0; i < 8; i++) {
      int r = wrow + 4 * i;
      float u0 = bf2f((unsigned short)(upf[i] & 0xFFFFu));
      float u1 = bf2f((unsigned short)(upf[i] >> 16));
      float v0 = bf2f((unsigned short)(vpf[i] & 0xFFFFu));
      float v1 = bf2f((unsigned short)(vpf[i] >> 16));
      float e0 = fmaxf(u0 + v0 + E[r][2 * cd] + bp0, 0.f);
      float e1 = fmaxf(u1 + v1 + E[r][2 * cd + 1] + bp1, 0.f);
      E[r][2 * cd] = e0;
      E[r][2 * cd + 1] = e1;
    }
    __syncthreads();  // B1.5: e ready for cross-row scan

    // ==== P2b: LDS-only segmented scan; stage next A + idx ====
    {
      unsigned int bm;
      {
        int l = lane & 31;
        int d = dstL[p][l];
        int dn = dstL[p][min(l + 1, 31)];
        bm = (unsigned int)__ballot(d != dn) | 0x80000000u;
      }
      float a0 = (half == 0) ? 0.f : -FLT_BIG;
      float a1 = (half == 0) ? 0.f : FLT_BIG;
      bool firstseg = true;
#pragma unroll
      for (int r = 0; r < 32; r++) {
        float e = E[r][c];
        if (half == 0) { a0 += e; a1 += e * e; }
        else { a0 = fmaxf(a0, e); a1 = fminf(a1, e); }
        if ((bm >> r) & 1u) {  // wave-uniform branch
          size_t o = (size_t)dstL[p][r] * 128 + c;
          bool bnd = firstseg || (r == 31);
          if (half == 0) {
            if (bnd) { atomicAdd(sum + o, a0); atomicAdd(sq + o, a1); }
            else { sum[o] = a0; sq[o] = a1; }
            a0 = 0.f; a1 = 0.f;
          } else {
            if (bnd) { atomicMax(mx + o, __float_as_uint(a0)); atomicMin(mn + o, __float_as_uint(a1)); }
            else { ((float*)mx)[o] = a0; ((float*)mn)[o] = a1; }
            a0 = -FLT_BIG; a1 = FLT_BIG;
          }
          firstseg = false;
        }
      }
    }
    WRITE_A();
    if (t < 32) { srcL[p ^ 1][t] = nsrc; dstL[p ^ 1][t] = ndst; }
    IDXLOAD(ch + 2 * G);
    __syncthreads();  // B2
    p ^= 1;
  }
}

// ---- post kernel: scaler-factored GEMM over K=640 (x | agg), fused MLP2 ----
__global__ __launch_bounds__(256) void post_kernel(
    const float* __restrict__ node_feat, const int* __restrict__ deg,
    const float* __restrict__ sum, const float* __restrict__ sq,
    const float* __restrict__ mxp, const float* __restrict__ mnp,
    const short* __restrict__ Wp1T, const short* __restrict__ Wp2T,
    const float* __restrict__ b1, const float* __restrict__ b2,
    float* __restrict__ out) {
  __shared__ short Ab[2][64][64];
  __shared__ short T[64][136];
  __shared__ float scalL[64][4];
  int t = threadIdx.x;
  int lane = t & 63, w = t >> 6;
  int r15 = lane & 15, g = lane >> 4;
  int nb = blockIdx.x * 64;

  if (t < 64) {
    int n = min(nb + t, N_NODES - 1);
    float dg = (float)deg[n];
    scalL[t][0] = 1.f / fmaxf(dg, 1.f);
    float logd = logf(dg + 1.f);
    scalL[t][1] = logd * 0.4f;
    scalL[t][2] = (dg > 0.f) ? 2.5f / fmaxf(logd, 1e-5f) : 0.f;
    scalL[t][3] = (dg > 0.f) ? 1.f : 0.f;
  }
  float bb1[2];
  bb1[0] = b1[2 * w * 16 + r15];
  bb1[1] = b1[(2 * w + 1) * 16 + r15];

  f32x4 accB[4][2], accC[4][2], accD[4][2];
#pragma unroll
  for (int m = 0; m < 4; m++)
#pragma unroll
    for (int j = 0; j < 2; j++) {
      accB[m][j] = (f32x4){0.f, 0.f, 0.f, 0.f};
      accC[m][j] = (f32x4){0.f, 0.f, 0.f, 0.f};
      accD[m][j] = (f32x4){0.f, 0.f, 0.f, 0.f};
    }

  auto STAGE = [&](int buf, int c) {
#pragma unroll
    for (int i = 0; i < 2; i++) {
      int row = i * 32 + (t >> 3);
      int gn = min(nb + row, N_NODES - 1);
      int s8 = t & 7;
      short* lp = &Ab[buf][0][0] + row * 64 + (s8 ^ (row & 7)) * 8;
      if (c < 2) {
        const float* np = node_feat + (size_t)gn * 128 + c * 64 + s8 * 8;
        float4v a = *(const float4v*)np, b = *(const float4v*)(np + 4);
        short8v pk;
#pragma unroll
        for (int r = 0; r < 4; r++) { pk[r] = f2bf(a[r]); pk[4 + r] = f2bf(b[r]); }
        *(short8v*)lp = pk;
      } else {
        size_t o = (size_t)gn * 128 + (c & 1) * 64 + s8 * 8;
        int si = (c - 2) >> 1;
        float inv = scalL[row][0], has = scalL[row][3];
        short8v pk;
        if (si == 0) {
          float4v a = *(const float4v*)(sum + o), b = *(const float4v*)(sum + o + 4);
#pragma unroll
          for (int r = 0; r < 4; r++) { pk[r] = f2bf(a[r] * inv); pk[4 + r] = f2bf(b[r] * inv); }
        } else if (si == 1) {
          float4v a = *(const float4v*)(mxp + o), b = *(const float4v*)(mxp + o + 4);
#pragma unroll
          for (int r = 0; r < 4; r++) { pk[r] = f2bf(a[r]); pk[4 + r] = f2bf(b[r]); }
        } else if (si == 2) {
          float4v a = *(const float4v*)(mnp + o), b = *(const float4v*)(mnp + o + 4);
          bool h = (has != 0.f);  // SELECT, not multiply (0*FLT_MAX safe, 0*inf was NaN)
#pragma unroll
          for (int r = 0; r < 4; r++) {
            pk[r] = f2bf(h ? a[r] : 0.f);
            pk[4 + r] = f2bf(h ? b[r] : 0.f);
          }
        } else {
          float4v a = *(const float4v*)(sum + o), b = *(const float4v*)(sum + o + 4);
          float4v qa = *(const float4v*)(sq + o), qb = *(const float4v*)(sq + o + 4);
#pragma unroll
          for (int r = 0; r < 4; r++) {
            float m0 = a[r] * inv, m1 = b[r] * inv;
            pk[r] = f2bf(has * sqrtf(fmaxf(qa[r] * inv - m0 * m0, 0.f) + 1e-5f));
            pk[4 + r] = f2bf(has * sqrtf(fmaxf(qb[r] * inv - m1 * m1, 0.f) + 1e-5f));
          }
        }
        *(short8v*)lp = pk;
      }
    }
  };

  auto COMPUTE = [&](int buf, int c) {
    const short* base = &Ab[buf][0][0];
#pragma unroll
    for (int ks2 = 0; ks2 < 2; ks2++) {
      short8v af[4];
#pragma unroll
      for (int m = 0; m < 4; m++) {
        int row = m * 16 + r15;
        af[m] = *(const short8v*)(base + row * 64 + (((ks2 << 2) | g) ^ (row & 7)) * 8);
      }
      if (c < 2) {
        int kcol = c * 64 + ks2 * 32;
#pragma unroll
        for (int j = 0; j < 2; j++) {
          short8v bf = *(const short8v*)(Wp1T + (size_t)((2 * w + j) * 16 + r15) * 1664 + kcol + 8 * g);
#pragma unroll
          for (int m = 0; m < 4; m++)
            accB[m][j] = __builtin_amdgcn_mfma_f32_16x16x32_bf16(af[m], bf, accB[m][j], 0, 0, 0);
        }
      } else {
        int kagg = (c - 2) * 64 + ks2 * 32;
#pragma unroll
        for (int j = 0; j < 2; j++) {
          const short* wr = Wp1T + (size_t)((2 * w + j) * 16 + r15) * 1664 + 8 * g;
          short8v bb = *(const short8v*)(wr + 128 + kagg);
          short8v bc = *(const short8v*)(wr + 640 + kagg);
          short8v bd = *(const short8v*)(wr + 1152 + kagg);
#pragma unroll
          for (int m = 0; m < 4; m++) {
            accB[m][j] = __builtin_amdgcn_mfma_f32_16x16x32_bf16(af[m], bb, accB[m][j], 0, 0, 0);
            accC[m][j] = __builtin_amdgcn_mfma_f32_16x16x32_bf16(af[m], bc, accC[m][j], 0, 0, 0);
            accD[m][j] = __builtin_amdgcn_mfma_f32_16x16x32_bf16(af[m], bd, accD[m][j], 0, 0, 0);
          }
        }
      }
    }
  };

  STAGE(0, 0);
  __syncthreads();
#pragma unroll
  for (int c = 0; c < 10; c++) {
    if (c < 9) STAGE((c + 1) & 1, c + 1);
    COMPUTE(c & 1, c);
    __syncthreads();
  }

#pragma unroll
  for (int m = 0; m < 4; m++)
#pragma unroll
    for (int j = 0; j < 2; j++)
#pragma unroll
      for (int r = 0; r < 4; r++) {
        int row = m * 16 + 4 * g + r;
        float v = accB[m][j][r] + scalL[row][1] * accC[m][j][r] + scalL[row][2] * accD[m][j][r] +
                  bb1[j];
        T[row][(2 * w + j) * 16 + r15] = f2bf(fmaxf(v, 0.f));
      }
  __syncthreads();

  f32x4 acc2[4][2];
#pragma unroll
  for (int m = 0; m < 4; m++)
#pragma unroll
    for (int j = 0; j < 2; j++) acc2[m][j] = (f32x4){0.f, 0.f, 0.f, 0.f};
#pragma unroll
  for (int ks = 0; ks < 4; ks++) {
    short8v af2[4], b2f[2];
#pragma unroll
    for (int m = 0; m < 4; m++) af2[m] = *(const short8v*)(&T[m * 16 + r15][ks * 32 + 8 * g]);
#pragma unroll
    for (int j = 0; j < 2; j++)
      b2f[j] = *(const short8v*)(Wp2T + (size_t)((2 * w + j) * 16 + r15) * 128 + ks * 32 + 8 * g);
#pragma unroll
    for (int m = 0; m < 4; m++)
#pragma unroll
      for (int j = 0; j < 2; j++)
        acc2[m][j] = __builtin_amdgcn_mfma_f32_16x16x32_bf16(af2[m], b2f[j], acc2[m][j], 0, 0, 0);
  }

#pragma unroll
  for (int m = 0; m < 4; m++)
#pragma unroll
    for (int j = 0; j < 2; j++)
#pragma unroll
      for (int r = 0; r < 4; r++) {
        int row = m * 16 + 4 * g + r;
        int gn = nb + row;
        if (gn < N_NODES) {
          int col = (2 * w + j) * 16 + r15;
          size_t o = (size_t)gn * 128 + col;
          out[o] = acc2[m][j][r] + b2[col] + node_feat[o];
        }
      }
}

extern "C" void kernel_launch(void* const* d_in, const int* in_sizes, int n_in,
                              void* d_out, int out_size, void* d_ws, size_t ws_size,
                              hipStream_t stream) {
  const float* node_feat = (const float*)d_in[0];
  const float* edge_feat = (const float*)d_in[1];
  const int* src = (const int*)d_in[2];
  const int* dst = (const int*)d_in[3];
  const float* W_pre = (const float*)d_in[4];
  const float* b_pre = (const float*)d_in[5];
  const float* W_post1 = (const float*)d_in[6];
  const float* b_post1 = (const float*)d_in[7];
  const float* W_post2 = (const float*)d_in[8];
  const float* b_post2 = (const float*)d_in[9];
  float* out = (float*)d_out;

  char* ws = (char*)d_ws;
  size_t P = (size_t)N_NODES * 128;
  float* sum = (float*)ws;
  float* sq = sum + P;
  float* mx = sq + P;
  float* mn = mx + P;
  int* deg = (int*)(mn + P);
  int* cursor = deg + 50048;
  int* perm = cursor + 50048;
  int* srcS = perm + 600064;
  int* dstS = srcS + 600064;
  short* UV = (short*)(dstS + 600064);   // 50048*256 bf16
  short* WuvT = UV + (size_t)50048 * 256;
  short* WeT = WuvT + 32768;
  short* Wp1T = WeT + 8192;
  short* Wp2T = Wp1T + 212992;
  size_t needed = (size_t)((char*)(Wp2T + 16384) - ws);
  if (ws_size < needed) return;

  init_kernel<<<2048, 256, 0, stream>>>((uint4v*)ws);
  conv_w_kernel<<<(270336 + 255) / 256, 256, 0, stream>>>(W_pre, W_post1, W_post2, WuvT, WeT,
                                                          Wp1T, Wp2T);
  deg_kernel<<<1024, 256, 0, stream>>>(dst, deg);
  scan_kernel<<<1, 1024, 0, stream>>>(deg, cursor);
  scatter_kernel<<<1024, 256, 0, stream>>>(src, dst, cursor, perm, srcS, dstS);
  uv_kernel<<<(N_NODES + 63) / 64, 256, 0, stream>>>(node_feat, WuvT, UV);
  edge_kernel<<<3750, 256, 0, stream>>>(perm, srcS, dstS, edge_feat, b_pre, UV, WeT, sum, sq,
                                        (unsigned int*)mx, (unsigned int*)mn);
  post_kernel<<<(N_NODES + 63) / 64, 256, 0, stream>>>(node_feat, deg, sum, sq, mx, mn, Wp1T,
                                                       Wp2T, b_post1, b_post2, out);
}

// Round 9
// 378.226 us; speedup vs baseline: 1.4471x; 1.0786x over previous
//
#include <hip/hip_runtime.h>
#include <hip/hip_bf16.h>
#include <math.h>

#define N_NODES 50000
#define N_EDGES 600000
// IN_DIM=128, EDGE_DIM=64; e = relu(U[src] + V[dst] + ef@We + b_pre)

typedef __attribute__((ext_vector_type(8))) short short8v;   // 8 bf16 MFMA A/B frag
typedef __attribute__((ext_vector_type(4))) short short4v;
typedef __attribute__((ext_vector_type(4))) float f32x4;     // MFMA C/D frag
typedef __attribute__((ext_vector_type(4))) float float4v;
typedef __attribute__((ext_vector_type(4))) unsigned int uint4v;

#define FLT_BIG 3.402823466e38f

__device__ __forceinline__ short f2bf(float f) {
  unsigned int u = __float_as_uint(f);
  u = (u + 0x7FFFu + ((u >> 16) & 1u)) >> 16;   // RNE
  return (short)u;
}
__device__ __forceinline__ float bf2f(unsigned short s) {
  return __uint_as_float(((unsigned int)s) << 16);
}

// ---- init: zero sum/sq/mx, FLT_MAX mn, zero deg (one kernel, 4 planes + deg)
__global__ void init_kernel(uint4v* __restrict__ base) {
  const long nz = 4800000;   // 3*P/4 uint4 (sum,sq,mx)
  const long nm = 1600000;   // P/4    (mn = FLT_MAX; NOT inf: 0*inf=NaN hazard)
  const long nd = 12512;     // deg 50048 ints
  uint4v z = {0u, 0u, 0u, 0u};
  uint4v f = {0x7F7FFFFFu, 0x7F7FFFFFu, 0x7F7FFFFFu, 0x7F7FFFFFu};
  long i = (long)blockIdx.x * blockDim.x + threadIdx.x;
  long stride = (long)gridDim.x * blockDim.x;
  for (; i < nz + nm + nd; i += stride) base[i] = (i >= nz && i < nz + nm) ? f : z;
}

// ---- weights: WuvT[256][128], WeT[128][64], Wp1T[128][1664], Wp2T[128][128]
__global__ void conv_w_kernel(const float* __restrict__ Wpre, const float* __restrict__ Wp1,
                              const float* __restrict__ Wp2, short* __restrict__ WuvT,
                              short* __restrict__ WeT, short* __restrict__ Wp1T,
                              short* __restrict__ Wp2T) {
  int idx = blockIdx.x * 256 + threadIdx.x;
  if (idx < 32768) {                       // WuvT: row c (<128:U, >=128:V), col k
    int c = idx >> 7, k = idx & 127;
    WuvT[idx] = f2bf(Wpre[(k + ((c >> 7) << 7)) * 128 + (c & 127)]);
  } else if (idx < 40960) {                // WeT
    int o = idx - 32768, n = o >> 6, k = o & 63;
    WeT[o] = f2bf(Wpre[(256 + k) * 128 + n]);
  } else if (idx < 253952) {               // Wp1T
    int o = idx - 40960, n = o / 1664, k = o % 1664;
    Wp1T[o] = f2bf(Wp1[k * 128 + n]);
  } else if (idx < 270336) {               // Wp2T
    int o = idx - 253952, n = o >> 7, k = o & 127;
    Wp2T[o] = f2bf(Wp2[k * 128 + n]);
  }
}

// ---- degree histogram ------------------------------------------------------
__global__ void deg_kernel(const int* __restrict__ dst, int* __restrict__ deg) {
  int i = blockIdx.x * blockDim.x + threadIdx.x;
  int stride = gridDim.x * blockDim.x;
  for (; i < N_EDGES; i += stride) atomicAdd(deg + dst[i], 1);
}

// ---- exclusive scan of deg -> cursor (single block) ------------------------
__global__ __launch_bounds__(1024) void scan_kernel(const int* __restrict__ deg,
                                                    int* __restrict__ cursor) {
  __shared__ int part[1024];
  const int CH = 49;
  int t = threadIdx.x;
  int base = t * CH;
  int s = 0;
  for (int i = 0; i < CH; i++) {
    int idx = base + i;
    if (idx < N_NODES) s += deg[idx];
  }
  part[t] = s;
  __syncthreads();
  for (int off = 1; off < 1024; off <<= 1) {
    int v = (t >= off) ? part[t - off] : 0;
    __syncthreads();
    part[t] += v;
    __syncthreads();
  }
  int ex = (t == 0) ? 0 : part[t - 1];
  for (int i = 0; i < CH; i++) {
    int idx = base + i;
    if (idx < N_NODES) {
      cursor[idx] = ex;
      ex += deg[idx];
    }
  }
}

// ---- scatter: perm + sorted src/dst ----------------------------------------
__global__ void scatter_kernel(const int* __restrict__ src, const int* __restrict__ dst,
                               int* __restrict__ cursor, int* __restrict__ perm,
                               int* __restrict__ srcS, int* __restrict__ dstS) {
  int i = blockIdx.x * blockDim.x + threadIdx.x;
  int stride = gridDim.x * blockDim.x;
  for (; i < N_EDGES; i += stride) {
    int d = dst[i];
    int pos = atomicAdd(cursor + d, 1);
    perm[pos] = i;
    srcS[pos] = src[i];
    dstS[pos] = d;
  }
}

// ---- UV kernel: [U|V] = x @ [Ws|Wd], dense 50K x 128 -> 256, bf16 out ------
__global__ __launch_bounds__(256) void uv_kernel(const float* __restrict__ nf,
                                                 const short* __restrict__ WuvT,
                                                 short* __restrict__ UV) {
  __shared__ short A[64][136];
  int t = threadIdx.x;
  int lane = t & 63, w = t >> 6;
  int r15 = lane & 15, g = lane >> 4;
  int nb = blockIdx.x * 64;

#pragma unroll
  for (int i = 0; i < 8; i++) {
    int u = t + 256 * i, row = u >> 5, q = u & 31;
    int gn = min(nb + row, N_NODES - 1);
    float4v a = *(const float4v*)(nf + (size_t)gn * 128 + q * 4);
    short4v s;
    s[0] = f2bf(a[0]); s[1] = f2bf(a[1]); s[2] = f2bf(a[2]); s[3] = f2bf(a[3]);
    *(short4v*)(&A[row][q * 4]) = s;
  }
  __syncthreads();

  f32x4 acc[4][4];
#pragma unroll
  for (int m = 0; m < 4; m++)
#pragma unroll
    for (int j = 0; j < 4; j++) acc[m][j] = (f32x4){0.f, 0.f, 0.f, 0.f};

#pragma unroll
  for (int ks = 0; ks < 4; ks++) {
    short8v af[4];
#pragma unroll
    for (int m = 0; m < 4; m++) af[m] = *(const short8v*)(&A[m * 16 + r15][ks * 32 + 8 * g]);
#pragma unroll
    for (int j = 0; j < 4; j++) {
      short8v bf = *(const short8v*)(WuvT + (size_t)((4 * w + j) * 16 + r15) * 128 + ks * 32 + 8 * g);
#pragma unroll
      for (int m = 0; m < 4; m++)
        acc[m][j] = __builtin_amdgcn_mfma_f32_16x16x32_bf16(af[m], bf, acc[m][j], 0, 0, 0);
    }
  }

#pragma unroll
  for (int m = 0; m < 4; m++)
#pragma unroll
    for (int j = 0; j < 4; j++)
#pragma unroll
      for (int r = 0; r < 4; r++) {
        int node = nb + m * 16 + 4 * g + r;
        if (node < N_NODES)
          UV[(size_t)node * 256 + (4 * w + j) * 16 + r15] = f2bf(acc[m][j][r]);
      }
}

// ---- edge kernel: full-chunk UV prefetch in P1; LDS-only serial scan -------
__global__ __launch_bounds__(256, 6) void edge_kernel(
    const int* __restrict__ perm, const int* __restrict__ srcS, const int* __restrict__ dstS,
    const float* __restrict__ edge_feat, const float* __restrict__ b_pre,
    const short* __restrict__ UV, const short* __restrict__ WeT,
    float* __restrict__ sum, float* __restrict__ sq,
    unsigned int* __restrict__ mx, unsigned int* __restrict__ mn) {
  __shared__ short A[32][72];        // 32 edges x 64 k (pad 8) = 4.6 KB
  __shared__ float E[32][132];       // F, then in-place e (pad 4) = 16.9 KB
  __shared__ int srcL[2][32], dstL[2][32];  // idx double-buffer, 512 B

  int t = threadIdx.x;
  int lane = t & 63, w = t >> 6;
  int r15 = lane & 15, g = lane >> 4;

  short8v bfr[2][2];                 // 16 VGPRs of We weights
#pragma unroll
  for (int ks = 0; ks < 2; ks++)
#pragma unroll
    for (int j = 0; j < 2; j++)
      bfr[ks][j] = *(const short8v*)(WeT + (size_t)((2 * w + j) * 16 + r15) * 64 + ks * 32 + 8 * g);

  int c = t & 127, half = t >> 7;    // scan role: col, stat-pair
  int cd = t & 63, wrow = t >> 6;    // e-compute role: col-pair, row-group
  float bp0 = b_pre[2 * cd], bp1 = b_pre[2 * cd + 1];

  const unsigned short* UVu = (const unsigned short*)UV;
  const int G = gridDim.x;
  const int nchunks = N_EDGES / 32;  // 18750
  int ch = blockIdx.x;
  if (ch >= nchunks) return;

  float4v ge[2];
  auto LOADE = [&](int chunk) {
    int e0c = min(chunk, nchunks - 1) * 32;
#pragma unroll
    for (int i = 0; i < 2; i++) {
      int u = t + 256 * i, e = u >> 4, q = u & 15;
      ge[i] = *(const float4v*)(edge_feat + (size_t)perm[e0c + e] * 64 + q * 4);
    }
  };
  auto WRITE_A = [&]() {
#pragma unroll
    for (int i = 0; i < 2; i++) {
      int u = t + 256 * i, e = u >> 4, q = u & 15;
      short4v s4;
      s4[0] = f2bf(ge[i][0]); s4[1] = f2bf(ge[i][1]);
      s4[2] = f2bf(ge[i][2]); s4[3] = f2bf(ge[i][3]);
      *(short4v*)(&A[e][q * 4]) = s4;
    }
  };

  int nsrc = 0, ndst = 0;
  auto IDXLOAD = [&](int chunk) {
    if (t < 32) {
      int e0c = min(chunk, nchunks - 1) * 32 + t;
      nsrc = srcS[e0c];
      ndst = dstS[e0c];
    }
  };

  // prologue: stage chunk ch (A + idx); preload idx(ch+G) into regs
  LOADE(ch);
  IDXLOAD(ch);
  if (t < 32) { srcL[0][t] = nsrc; dstL[0][t] = ndst; }
  WRITE_A();
  IDXLOAD(ch + G);
  __syncthreads();

  int p = 0;
  for (; ch < nchunks; ch += G) {
    // ==== P1: issue whole-chunk UV prefetch (16 dwords/thread); MFMA; ====
    // ==== issue next-chunk edge gathers.  Loads land by B1's vmcnt drain. ===
    unsigned int upf[8], vpf[8];
#pragma unroll
    for (int i = 0; i < 8; i++) {
      int r = wrow + 4 * i;
      int sr = srcL[p][r], dr = dstL[p][r];
      upf[i] = *(const unsigned int*)(UVu + (size_t)sr * 256 + 2 * cd);
      vpf[i] = *(const unsigned int*)(UVu + (size_t)dr * 256 + 128 + 2 * cd);
    }
    LOADE(ch + G);

    f32x4 acc[2][2];
#pragma unroll
    for (int m = 0; m < 2; m++)
#pragma unroll
      for (int j = 0; j < 2; j++) acc[m][j] = (f32x4){0.f, 0.f, 0.f, 0.f};
#pragma unroll
    for (int m = 0; m < 2; m++)
#pragma unroll
      for (int ks = 0; ks < 2; ks++) {
        short8v af = *(const short8v*)(&A[m * 16 + r15][ks * 32 + 8 * g]);
        acc[m][0] = __builtin_amdgcn_mfma_f32_16x16x32_bf16(af, bfr[ks][0], acc[m][0], 0, 0, 0);
        acc[m][1] = __builtin_amdgcn_mfma_f32_16x16x32_bf16(af, bfr[ks][1], acc[m][1], 0, 0, 0);
      }
#pragma unroll
    for (int m = 0; m < 2; m++)
#pragma unroll
      for (int j = 0; j < 2; j++)
#pragma unroll
        for (int r = 0; r < 4; r++)
          E[m * 16 + 4 * g + r][(2 * w + j) * 16 + r15] = acc[m][j][r];
    __syncthreads();  // B1: E(F) ready; A free; all prefetches landed

    // ==== P2a: e = relu(u + v + F + b) in place (pure VALU + LDS) ====
#pragma unroll
    for (int i = 0; i < 8; i++) {
      int r = wrow + 4 * i;
      float u0 = bf2f((unsigned short)(upf[i] & 0xFFFFu));
      float u1 = bf2f((unsigned short)(upf[i] >> 16));
      float v0 = bf2f((unsigned short)(vpf[i] & 0xFFFFu));
      float v1 = bf2f((unsigned short)(vpf[i] >> 16));
      float e0 = fmaxf(u0 + v0 + E[r][2 * cd] + bp0, 0.f);
      float e1 = fmaxf(u1 + v1 + E[r][2 * cd + 1] + bp1, 0.f);
      E[r][2 * cd] = e0;
      E[r][2 * cd + 1] = e1;
    }
    __syncthreads();  // B1.5: e ready for cross-row scan

    // ==== P2b: LDS-only segmented scan; stage next A + idx ====
    {
      unsigned int bm;
      {
        int l = lane & 31;
        int d = dstL[p][l];
        int dn = dstL[p][min(l + 1, 31)];
        bm = (unsigned int)__ballot(d != dn) | 0x80000000u;
      }
      float a0 = (half == 0) ? 0.f : -FLT_BIG;
      float a1 = (half == 0) ? 0.f : FLT_BIG;
      bool firstseg = true;
#pragma unroll
      for (int r = 0; r < 32; r++) {
        float e = E[r][c];
        if (half == 0) { a0 += e; a1 += e * e; }
        else { a0 = fmaxf(a0, e); a1 = fminf(a1, e); }
        if ((bm >> r) & 1u) {  // wave-uniform branch
          size_t o = (size_t)dstL[p][r] * 128 + c;
          bool bnd = firstseg || (r == 31);
          if (half == 0) {
            if (bnd) { atomicAdd(sum + o, a0); atomicAdd(sq + o, a1); }
            else { sum[o] = a0; sq[o] = a1; }
            a0 = 0.f; a1 = 0.f;
          } else {
            if (bnd) { atomicMax(mx + o, __float_as_uint(a0)); atomicMin(mn + o, __float_as_uint(a1)); }
            else { ((float*)mx)[o] = a0; ((float*)mn)[o] = a1; }
            a0 = -FLT_BIG; a1 = FLT_BIG;
          }
          firstseg = false;
        }
      }
    }
    WRITE_A();
    if (t < 32) { srcL[p ^ 1][t] = nsrc; dstL[p ^ 1][t] = ndst; }
    IDXLOAD(ch + 2 * G);
    __syncthreads();  // B2
    p ^= 1;
  }
}

// ---- post kernel v2: 512 thr / 8 waves, VGPR<=128 (16 waves/CU), ----------
// runtime chunk loop, issue-early/write-late pipeline, 1 barrier/chunk.
// h@W1 = x@W1[0:128] + agg@W1[128:640] + ampf*(agg@W1[640:1152]) + attf*(...)
__global__ __launch_bounds__(512, 4) void post_kernel(
    const float* __restrict__ node_feat, const int* __restrict__ deg,
    const float* __restrict__ sum, const float* __restrict__ sq,
    const float* __restrict__ mxp, const float* __restrict__ mnp,
    const short* __restrict__ Wp1T, const short* __restrict__ Wp2T,
    const float* __restrict__ b1, const float* __restrict__ b2,
    float* __restrict__ out) {
  __shared__ short Ab[2][64][64];  // double-buffered 64x64 A-tile (XOR-swizzled 16B slots)
  __shared__ short T[64][136];     // relu(h@W1+b1) bf16 (pad 8)
  __shared__ float scalL[64][4];   // inv_safe_deg, ampf, attf, has
  int t = threadIdx.x;             // 0..511
  int lane = t & 63, w = t >> 6;   // 8 waves, wave w owns n-cols w*16..w*16+15
  int r15 = lane & 15, g = lane >> 4;
  int nb = blockIdx.x * 64;

  if (t < 64) {
    int n = min(nb + t, N_NODES - 1);
    float dg = (float)deg[n];
    scalL[t][0] = 1.f / fmaxf(dg, 1.f);
    float logd = logf(dg + 1.f);
    scalL[t][1] = logd * 0.4f;
    scalL[t][2] = (dg > 0.f) ? 2.5f / fmaxf(logd, 1e-5f) : 0.f;
    scalL[t][3] = (dg > 0.f) ? 1.f : 0.f;
  }
  float bb1v = b1[w * 16 + r15];

  // staging role: one row, 8 cols per thread (512 = 64 rows x 8 col-groups)
  int srow = t >> 3, s8 = t & 7;
  int sgn = min(nb + srow, N_NODES - 1);
  float4v ra, rb, qa, qb;  // stat prefetch regs (issued early, consumed late)

  auto PRE = [&](int c) {  // issue global loads for chunk c
    if (c < 2) {
      const float* np = node_feat + (size_t)sgn * 128 + c * 64 + s8 * 8;
      ra = *(const float4v*)np;
      rb = *(const float4v*)(np + 4);
    } else {
      size_t o = (size_t)sgn * 128 + (c & 1) * 64 + s8 * 8;
      int si = (c - 2) >> 1;
      if (si == 0) { ra = *(const float4v*)(sum + o); rb = *(const float4v*)(sum + o + 4); }
      else if (si == 1) { ra = *(const float4v*)(mxp + o); rb = *(const float4v*)(mxp + o + 4); }
      else if (si == 2) { ra = *(const float4v*)(mnp + o); rb = *(const float4v*)(mnp + o + 4); }
      else {
        ra = *(const float4v*)(sum + o); rb = *(const float4v*)(sum + o + 4);
        qa = *(const float4v*)(sq + o);  qb = *(const float4v*)(sq + o + 4);
      }
    }
  };
  auto WR = [&](int buf, int c) {  // cvt + LDS write for chunk c
    short8v pk;
    if (c < 2) {
#pragma unroll
      for (int r = 0; r < 4; r++) { pk[r] = f2bf(ra[r]); pk[4 + r] = f2bf(rb[r]); }
    } else {
      int si = (c - 2) >> 1;
      float inv = scalL[srow][0], has = scalL[srow][3];
      if (si == 0) {
#pragma unroll
        for (int r = 0; r < 4; r++) { pk[r] = f2bf(ra[r] * inv); pk[4 + r] = f2bf(rb[r] * inv); }
      } else if (si == 1) {
#pragma unroll
        for (int r = 0; r < 4; r++) { pk[r] = f2bf(ra[r]); pk[4 + r] = f2bf(rb[r]); }
      } else if (si == 2) {
        bool h = (has != 0.f);  // SELECT, not multiply (0*FLT_MAX safe, 0*inf was NaN)
#pragma unroll
        for (int r = 0; r < 4; r++) {
          pk[r] = f2bf(h ? ra[r] : 0.f);
          pk[4 + r] = f2bf(h ? rb[r] : 0.f);
        }
      } else {
#pragma unroll
        for (int r = 0; r < 4; r++) {
          float m0 = ra[r] * inv, m1 = rb[r] * inv;
          pk[r] = f2bf(has * sqrtf(fmaxf(qa[r] * inv - m0 * m0, 0.f) + 1e-5f));
          pk[4 + r] = f2bf(has * sqrtf(fmaxf(qb[r] * inv - m1 * m1, 0.f) + 1e-5f));
        }
      }
    }
    *(short8v*)(&Ab[buf][0][0] + srow * 64 + (s8 ^ (srow & 7)) * 8) = pk;
  };

  f32x4 accB[4], accC[4], accD[4];
#pragma unroll
  for (int m = 0; m < 4; m++) {
    accB[m] = (f32x4){0.f, 0.f, 0.f, 0.f};
    accC[m] = (f32x4){0.f, 0.f, 0.f, 0.f};
    accD[m] = (f32x4){0.f, 0.f, 0.f, 0.f};
  }

  const short* wrp = Wp1T + (size_t)(w * 16 + r15) * 1664 + 8 * g;

  // prologue
  PRE(0);
  __syncthreads();   // scalL visible
  WR(0, 0);
  __syncthreads();   // Ab[0] ready

  for (int c = 0; c < 10; c++) {
    int buf = c & 1;
    if (c < 9) PRE(c + 1);  // issue next-chunk stat loads (land during MFMA)
    // weight frags for this chunk (L2-resident)
    short8v bw0[3], bw1[3];
    if (c < 2) {
      bw0[0] = *(const short8v*)(wrp + c * 64);
      bw1[0] = *(const short8v*)(wrp + c * 64 + 32);
    } else {
      int ka = (c - 2) * 64;
      bw0[0] = *(const short8v*)(wrp + 128 + ka);
      bw0[1] = *(const short8v*)(wrp + 640 + ka);
      bw0[2] = *(const short8v*)(wrp + 1152 + ka);
      bw1[0] = *(const short8v*)(wrp + 128 + ka + 32);
      bw1[1] = *(const short8v*)(wrp + 640 + ka + 32);
      bw1[2] = *(const short8v*)(wrp + 1152 + ka + 32);
    }
    const short* base = &Ab[buf][0][0];
#pragma unroll
    for (int ks2 = 0; ks2 < 2; ks2++) {
      const short8v* bw = (ks2 == 0) ? bw0 : bw1;
      short8v af[4];
#pragma unroll
      for (int m = 0; m < 4; m++) {
        int row = m * 16 + r15;
        af[m] = *(const short8v*)(base + row * 64 + (((ks2 << 2) | g) ^ (row & 7)) * 8);
      }
      if (c < 2) {
#pragma unroll
        for (int m = 0; m < 4; m++)
          accB[m] = __builtin_amdgcn_mfma_f32_16x16x32_bf16(af[m], bw[0], accB[m], 0, 0, 0);
      } else {
#pragma unroll
        for (int m = 0; m < 4; m++) {
          accB[m] = __builtin_amdgcn_mfma_f32_16x16x32_bf16(af[m], bw[0], accB[m], 0, 0, 0);
          accC[m] = __builtin_amdgcn_mfma_f32_16x16x32_bf16(af[m], bw[1], accC[m], 0, 0, 0);
          accD[m] = __builtin_amdgcn_mfma_f32_16x16x32_bf16(af[m], bw[2], accD[m], 0, 0, 0);
        }
      }
    }
    if (c < 9) WR(buf ^ 1, c + 1);  // write-late: after MFMA, before barrier
    __syncthreads();
  }

  // combine with per-node scalers, bias, relu -> T (bf16)
#pragma unroll
  for (int m = 0; m < 4; m++)
#pragma unroll
    for (int r = 0; r < 4; r++) {
      int row = m * 16 + 4 * g + r;
      float v = accB[m][r] + scalL[row][1] * accC[m][r] + scalL[row][2] * accD[m][r] + bb1v;
      T[row][w * 16 + r15] = f2bf(fmaxf(v, 0.f));
    }
  __syncthreads();

  f32x4 acc2[4];
#pragma unroll
  for (int m = 0; m < 4; m++) acc2[m] = (f32x4){0.f, 0.f, 0.f, 0.f};
#pragma unroll
  for (int ks = 0; ks < 4; ks++) {
    short8v af2[4];
#pragma unroll
    for (int m = 0; m < 4; m++) af2[m] = *(const short8v*)(&T[m * 16 + r15][ks * 32 + 8 * g]);
    short8v b2f = *(const short8v*)(Wp2T + (size_t)(w * 16 + r15) * 128 + ks * 32 + 8 * g);
#pragma unroll
    for (int m = 0; m < 4; m++)
      acc2[m] = __builtin_amdgcn_mfma_f32_16x16x32_bf16(af2[m], b2f, acc2[m], 0, 0, 0);
  }

#pragma unroll
  for (int m = 0; m < 4; m++)
#pragma unroll
    for (int r = 0; r < 4; r++) {
      int row = m * 16 + 4 * g + r;
      int gn = nb + row;
      if (gn < N_NODES) {
        int col = w * 16 + r15;
        size_t o = (size_t)gn * 128 + col;
        out[o] = acc2[m][r] + b2[col] + node_feat[o];
      }
    }
}

extern "C" void kernel_launch(void* const* d_in, const int* in_sizes, int n_in,
                              void* d_out, int out_size, void* d_ws, size_t ws_size,
                              hipStream_t stream) {
  const float* node_feat = (const float*)d_in[0];
  const float* edge_feat = (const float*)d_in[1];
  const int* src = (const int*)d_in[2];
  const int* dst = (const int*)d_in[3];
  const float* W_pre = (const float*)d_in[4];
  const float* b_pre = (const float*)d_in[5];
  const float* W_post1 = (const float*)d_in[6];
  const float* b_post1 = (const float*)d_in[7];
  const float* W_post2 = (const float*)d_in[8];
  const float* b_post2 = (const float*)d_in[9];
  float* out = (float*)d_out;

  char* ws = (char*)d_ws;
  size_t P = (size_t)N_NODES * 128;
  float* sum = (float*)ws;
  float* sq = sum + P;
  float* mx = sq + P;
  float* mn = mx + P;
  int* deg = (int*)(mn + P);
  int* cursor = deg + 50048;
  int* perm = cursor + 50048;
  int* srcS = perm + 600064;
  int* dstS = srcS + 600064;
  short* UV = (short*)(dstS + 600064);   // 50048*256 bf16
  short* WuvT = UV + (size_t)50048 * 256;
  short* WeT = WuvT + 32768;
  short* Wp1T = WeT + 8192;
  short* Wp2T = Wp1T + 212992;
  size_t needed = (size_t)((char*)(Wp2T + 16384) - ws);
  if (ws_size < needed) return;

  init_kernel<<<2048, 256, 0, stream>>>((uint4v*)ws);
  conv_w_kernel<<<(270336 + 255) / 256, 256, 0, stream>>>(W_pre, W_post1, W_post2, WuvT, WeT,
                                                          Wp1T, Wp2T);
  deg_kernel<<<1024, 256, 0, stream>>>(dst, deg);
  scan_kernel<<<1, 1024, 0, stream>>>(deg, cursor);
  scatter_kernel<<<1024, 256, 0, stream>>>(src, dst, cursor, perm, srcS, dstS);
  uv_kernel<<<(N_NODES + 63) / 64, 256, 0, stream>>>(node_feat, WuvT, UV);
  edge_kernel<<<3750, 256, 0, stream>>>(perm, srcS, dstS, edge_feat, b_pre, UV, WeT, sum, sq,
                                        (unsigned int*)mx, (unsigned int*)mn);
  post_kernel<<<(N_NODES + 63) / 64, 512, 0, stream>>>(node_feat, deg, sum, sq, mx, mn, Wp1T,
                                                       Wp2T, b_post1, b_post2, out);
}